// Round 5
// baseline (332.860 us; speedup 1.0000x reference)
//
#include <hip/hip_runtime.h>
#include <hip/hip_bf16.h>
#include <stdint.h>

// B=16, N=4096, H=512, K=2H=1024
//   pf[b,n,h]   = sum_k features[b,n,k] * Wf[h,k]
//   pq[b,h]     = sum_k query[b,k] * Wq[h,k]
//   logits[b,n] = 10*tanh( sum_h v[h]*tanh(pf+pq) )
// Outputs: pf (33554432 f32) then logits (65536 f32).
// R5: pure-register dataflow. No LDS in the K-loop, no barriers, no
// global_load_lds, no manual vmcnt. B (Wf) pre-shuffled to MFMA fragment
// order in ws (1MB, L2-resident); A loaded fp32 direct to regs (4 waves of
// a block share the same 32 rows -> L1 reuse) and converted via v_cvt_pk.
// 1-deep ping-pong prefetch for both A and B; compiler inserts precise
// per-register waitcnts; waves free-run. acc 32x128/wave = 64 AGPR;
// launch_bounds(256,3) targets 3 waves/SIMD (~164 total regs).

#define KDIM 1024
#define HDIM 512

typedef short bf16x8 __attribute__((ext_vector_type(8)));
typedef float f32x4  __attribute__((ext_vector_type(4)));

__device__ __forceinline__ float fast_tanh(float x) {
    float ax = fabsf(x);
    float e  = __expf(-2.0f * ax);
    float r  = (1.0f - e) / (1.0f + e);
    return copysignf(r, x);
}

__device__ __forceinline__ short f2bf(float x) {
    __hip_bfloat16 b = __float2bfloat16(x);
    return (short)__builtin_bit_cast(unsigned short, b);
}

__device__ __forceinline__ bf16x8 cvt8(float4 a, float4 b) {
    bf16x8 o;
    o[0] = f2bf(a.x); o[1] = f2bf(a.y); o[2] = f2bf(a.z); o[3] = f2bf(a.w);
    o[4] = f2bf(b.x); o[5] = f2bf(b.y); o[6] = f2bf(b.z); o[7] = f2bf(b.w);
    return o;
}

// ---------------- Wf -> bf16 MFMA-fragment order ----------------
// chunk tid = (kt*32 + gg)*64 + lane, lane = fkg*16 + fm:
// content = Wf[col = gg*16+fm][kt*32 + fkg*8 .. +8] as bf16x8.
__global__ void bshuf_kernel(const float* __restrict__ Wf, short* __restrict__ Bsh) {
    const int tid = blockIdx.x * 256 + threadIdx.x;   // 0..65535
    const int kt  = tid >> 11;
    const int gg  = (tid >> 6) & 31;
    const int ln  = tid & 63;
    const int fm  = ln & 15, fkg = ln >> 4;
    const int col = gg * 16 + fm;
    const int k0  = kt * 32 + fkg * 8;
    const float* src = Wf + col * KDIM + k0;
    float4 a = *(const float4*)src;
    float4 b = *(const float4*)(src + 4);
    *(bf16x8*)(Bsh + (size_t)tid * 8) = cvt8(a, b);
}

// ---------------- tiny GEMM: pq[b,h] ----------------
__global__ void pq_kernel(const float* __restrict__ query,
                          const float* __restrict__ Wq,
                          float* __restrict__ pq) {
    const int t = blockIdx.x * blockDim.x + threadIdx.x;   // 8192
    const int b = t >> 9, h = t & 511;
    const float4* q  = (const float4*)(query + (b << 9));
    const float4* wq = (const float4*)(Wq + ((size_t)h << 9));
    float s = 0.0f;
    #pragma unroll 4
    for (int i = 0; i < 128; ++i) {
        float4 a = q[i], c = wq[i];
        s += a.x * c.x + a.y * c.y + a.z * c.z + a.w * c.w;
    }
    pq[t] = s;
}

// ---------------- main GEMM + fused epilogue ----------------
// 256 threads = 4 waves (n-split). Block tile 32 x 512, wave tile 32 x 128.
// 2048 blocks. K-loop: 32 steps, 1-deep ping-pong reg prefetch, no sync.
__global__ __launch_bounds__(256, 3) void gemm_kernel(
    const float* __restrict__ A, const short* __restrict__ Bsh,
    const float* __restrict__ pq, const float* __restrict__ v,
    float* __restrict__ pf, float* __restrict__ logits)
{
    __shared__ float uls[128];        // 32 rows x 4 waves (epilogue only)
    const int t    = threadIdx.x;
    const int lane = t & 63;
    const int w    = t >> 6;          // wave -> cols w*128..+128
    const int fm   = lane & 15;
    const int fkg  = lane >> 4;       // k subgroup 0..3
    const int Mbase = blockIdx.x * 32;

    // A row pointers for the two m-fragments (f=0: rows 0-15, f=1: 16-31)
    const float* a0 = A + (size_t)(Mbase + fm) * KDIM + fkg * 8;
    const float* a1 = a0 + 16 * KDIM;
    // B fragment base: chunk (gg*64 + lane) with gg = w*8+g, kt stride 32KB
    const char* Bb = (const char*)Bsh + ((size_t)(w * 8 * 64) + lane) * 16;

    f32x4 acc[2][8];
    const f32x4 zf = {0.0f, 0.0f, 0.0f, 0.0f};
    #pragma unroll
    for (int f = 0; f < 2; ++f)
        #pragma unroll
        for (int g = 0; g < 8; ++g) acc[f][g] = zf;

    float4 aFX[4], aFY[4];
    bf16x8 bX[8], bY[8];
    bf16x8 abf[2];

    #define LOAD_A(DST, KT) do {                                             \
        const int k4 = ((KT) & 31) * 8;      /* kt*32 floats = kt*8 float4 */\
        DST[0] = ((const float4*)a0)[k4];                                    \
        DST[1] = ((const float4*)a0)[k4 + 1];                                \
        DST[2] = ((const float4*)a1)[k4];                                    \
        DST[3] = ((const float4*)a1)[k4 + 1];                                \
    } while (0)

    #define LOAD_B(DST, KT) do {                                             \
        const char* bk = Bb + (size_t)(((KT) & 31)) * 32768;                 \
        _Pragma("unroll")                                                    \
        for (int g = 0; g < 8; ++g)                                          \
            DST[g] = *(const bf16x8*)(bk + g * 1024);                        \
    } while (0)

    #define BODY(KT, AC, BC, AN, BN) do {                                    \
        LOAD_A(AN, (KT) + 1);                                                \
        LOAD_B(BN, (KT) + 1);                                                \
        abf[0] = cvt8(AC[0], AC[1]);                                         \
        abf[1] = cvt8(AC[2], AC[3]);                                         \
        _Pragma("unroll")                                                    \
        for (int f = 0; f < 2; ++f)                                          \
            _Pragma("unroll")                                                \
            for (int g = 0; g < 8; ++g)                                      \
                acc[f][g] = __builtin_amdgcn_mfma_f32_16x16x32_bf16(         \
                    abf[f], BC[g], acc[f][g], 0, 0, 0);                      \
    } while (0)

    LOAD_A(aFX, 0);
    LOAD_B(bX, 0);

    #pragma unroll 1
    for (int kt2 = 0; kt2 < 16; ++kt2) {
        BODY(2 * kt2,     aFX, bX, aFY, bY);
        BODY(2 * kt2 + 1, aFY, bY, aFX, bX);
    }
    #undef LOAD_A
    #undef LOAD_B
    #undef BODY

    // ---- fused epilogue: pf store + u partials ----
    const int bidx = Mbase >> 12;
    const float* pqb = pq + (bidx << 9);
    float vv[8], pv[8];
    #pragma unroll
    for (int g = 0; g < 8; ++g) {
        const int c = w * 128 + g * 16 + fm;
        vv[g] = v[c];
        pv[g] = pqb[c];
    }
    #pragma unroll
    for (int f = 0; f < 2; ++f) {
        #pragma unroll
        for (int rr = 0; rr < 4; ++rr) {
            const int rloc = f * 16 + fkg * 4 + rr;
            float* prow = pf + (size_t)(Mbase + rloc) * HDIM + w * 128 + fm;
            float s = 0.0f;
            #pragma unroll
            for (int g = 0; g < 8; ++g) {
                const float val = acc[f][g][rr];
                __builtin_nontemporal_store(val, &prow[g * 16]);
                s += vv[g] * fast_tanh(val + pv[g]);
            }
            s += __shfl_xor(s, 1);
            s += __shfl_xor(s, 2);
            s += __shfl_xor(s, 4);
            s += __shfl_xor(s, 8);
            if (fm == 0) uls[rloc * 4 + w] = s;
        }
    }
    __syncthreads();
    if (t < 32) {
        const float4 p4 = *(const float4*)(uls + t * 4);
        const float u = p4.x + p4.y + p4.z + p4.w;
        logits[Mbase + t] = 10.0f * fast_tanh(u);
    }
}

extern "C" void kernel_launch(void* const* d_in, const int* in_sizes, int n_in,
                              void* d_out, int out_size, void* d_ws, size_t ws_size,
                              hipStream_t stream) {
    const float* features = (const float*)d_in[0];
    const float* query    = (const float*)d_in[1];
    const float* Wf       = (const float*)d_in[2];
    const float* Wq       = (const float*)d_in[3];
    const float* v        = (const float*)d_in[4];

    float* pf     = (float*)d_out;
    float* logits = (float*)d_out + 33554432;

    float* ws_pq  = (float*)d_ws;                    // 8192 f32  (32KB)
    short* ws_bsh = (short*)(ws_pq + 8192);          // 524288 bf16 (1MB)

    bshuf_kernel<<<256, 256, 0, stream>>>(Wf, ws_bsh);
    pq_kernel<<<16, 512, 0, stream>>>(query, Wq, ws_pq);
    gemm_kernel<<<2048, 256, 0, stream>>>(features, ws_bsh, ws_pq, v, pf, logits);
}

// Round 6
// 191.775 us; speedup vs baseline: 1.7357x; 1.7357x over previous
//
#include <hip/hip_runtime.h>
#include <hip/hip_bf16.h>
#include <stdint.h>

// B=16, N=4096, H=512, K=2H=1024
//   pf[b,n,h]   = sum_k features[b,n,k] * Wf[h,k]
//   pq[b,h]     = sum_k query[b,k] * Wq[h,k]
//   logits[b,n] = 10*tanh( sum_h v[h]*tanh(pf+pq) )
// Outputs: pf (33554432 f32) then logits (65536 f32).
// R6 = R4 staging + R5 tile, sized by Little's law:
//  - 32x512 block tile, 4 waves (n-split), wave tile 32x128, acc=64 AGPR,
//    launch_bounds(256,3) -> 3 waves/SIMD (12 waves/CU).
//  - A fp32 staged via global_load_lds (coalesced inverse-swizzled source,
//    linear LDS dest, 1 gll/thread/kt), QUAD-buffered, stage-ahead-2:
//    uniform s_waitcnt vmcnt(10) waits ONLY the 2-step-old gll (never
//    current B loads / just-issued stage), one raw s_barrier per kt.
//    Outstanding/CU ~ 24KB >= ~22KB needed for 6.3TB/s at ~900cy latency.
//  - B (Wf) pre-shuffled to MFMA fragment order in ws (L2-hot), 8 coalesced
//    reg loads issued at step start, consumed at step end.

#define KDIM 1024
#define HDIM 512

typedef short bf16x8 __attribute__((ext_vector_type(8)));
typedef float f32x4  __attribute__((ext_vector_type(4)));

__device__ __forceinline__ float fast_tanh(float x) {
    float ax = fabsf(x);
    float e  = __expf(-2.0f * ax);
    float r  = (1.0f - e) / (1.0f + e);
    return copysignf(r, x);
}

__device__ __forceinline__ short f2bf(float x) {
    __hip_bfloat16 b = __float2bfloat16(x);
    return (short)__builtin_bit_cast(unsigned short, b);
}

__device__ __forceinline__ bf16x8 cvt8(float4 a, float4 b) {
    bf16x8 o;
    o[0] = f2bf(a.x); o[1] = f2bf(a.y); o[2] = f2bf(a.z); o[3] = f2bf(a.w);
    o[4] = f2bf(b.x); o[5] = f2bf(b.y); o[6] = f2bf(b.z); o[7] = f2bf(b.w);
    return o;
}

// ---------------- Wf -> bf16 MFMA-fragment order ----------------
// chunk tid = (kt*32 + gg)*64 + lane, lane = fkg*16 + fm:
// content = Wf[col = gg*16+fm][kt*32 + fkg*8 .. +8] as bf16x8.
__global__ void bshuf_kernel(const float* __restrict__ Wf, short* __restrict__ Bsh) {
    const int tid = blockIdx.x * 256 + threadIdx.x;   // 0..65535
    const int kt  = tid >> 11;
    const int gg  = (tid >> 6) & 31;
    const int ln  = tid & 63;
    const int fm  = ln & 15, fkg = ln >> 4;
    const int col = gg * 16 + fm;
    const int k0  = kt * 32 + fkg * 8;
    const float* src = Wf + col * KDIM + k0;
    float4 a = *(const float4*)src;
    float4 b = *(const float4*)(src + 4);
    *(bf16x8*)(Bsh + (size_t)tid * 8) = cvt8(a, b);
}

// ---------------- tiny GEMM: pq[b,h] ----------------
__global__ void pq_kernel(const float* __restrict__ query,
                          const float* __restrict__ Wq,
                          float* __restrict__ pq) {
    const int t = blockIdx.x * blockDim.x + threadIdx.x;   // 8192
    const int b = t >> 9, h = t & 511;
    const float4* q  = (const float4*)(query + (b << 9));
    const float4* wq = (const float4*)(Wq + ((size_t)h << 9));
    float s = 0.0f;
    #pragma unroll 4
    for (int i = 0; i < 128; ++i) {
        float4 a = q[i], c = wq[i];
        s += a.x * c.x + a.y * c.y + a.z * c.z + a.w * c.w;
    }
    pq[t] = s;
}

// ---------------- main GEMM + fused epilogue ----------------
// 2048 blocks x 256 thr (4 waves, n-split). Block tile 32x512, BK=32.
__global__ __launch_bounds__(256, 3) void gemm_kernel(
    const float* __restrict__ A, const short* __restrict__ Bsh,
    const float* __restrict__ pq, const float* __restrict__ v,
    float* __restrict__ pf, float* __restrict__ logits)
{
    __shared__ __align__(16) char ldsA[4][4096];   // quad-buffer: 32 rows x 128B
    __shared__ float uls[128];                     // 32 rows x 4 waves
    const int t    = threadIdx.x;
    const int lane = t & 63;
    const int w    = t >> 6;          // wave -> cols w*128..+128
    const int fm   = lane & 15;
    const int fkg  = lane >> 4;       // 0..3
    const int Mbase = blockIdx.x * 32;

    // ---- A staging: thread t fills LDS chunk t (linear dest) from the
    // inverse-swizzled global chunk: LDS(row,sp) holds global (row, sp^(row&7)).
    const int srow = t >> 3, sp = t & 7;
    const int asrc = srow * 4096 + ((sp ^ (srow & 7)) << 4);
    const int adst = t * 16;
    const char* Ab = (const char*)(A + (size_t)Mbase * KDIM);

    // ---- A fragment ds_read offsets: rows {fm, fm+16}, logical slots
    // {fkg*2, fkg*2+1}; addr(r,s) = r*128 + ((s ^ (r&7))<<4).
    int ard[2][2];
    #pragma unroll
    for (int f = 0; f < 2; ++f) {
        const int r = f * 16 + fm;
        ard[f][0] = r * 128 + (((fkg * 2    ) ^ (r & 7)) << 4);
        ard[f][1] = r * 128 + (((fkg * 2 + 1) ^ (r & 7)) << 4);
    }

    // ---- B fragment base (fragment-order ws): chunk (w*8+g)*64+lane, kt*32KB
    const char* Bb = (const char*)Bsh + ((size_t)(w * 8 * 64) + lane) * 16;

    f32x4 acc[2][8];
    const f32x4 zf = {0.0f, 0.0f, 0.0f, 0.0f};
    #pragma unroll
    for (int f = 0; f < 2; ++f)
        #pragma unroll
        for (int g = 0; g < 8; ++g) acc[f][g] = zf;

    #define STAGE(BUF, KT) \
        __builtin_amdgcn_global_load_lds( \
            (const __attribute__((address_space(1))) void*)(Ab + asrc + ((KT) & 31) * 128), \
            (__attribute__((address_space(3))) void*)(&ldsA[BUF][adst]), 16, 0, 0)

    STAGE(0, 0);
    STAGE(1, 1);

    bf16x8 bfr[8], abf[2];

    #pragma unroll 2
    for (int kt = 0; kt < 32; ++kt) {
        // B(kt): 8 coalesced 16B loads (L2-hot); consumed at MFMA below.
        const char* bk = Bb + (size_t)kt * 32768;
        #pragma unroll
        for (int g = 0; g < 8; ++g)
            bfr[g] = *(const bf16x8*)(bk + g * 1024);
        // stage A(kt+2) (tail wraps to a dummy in-bounds reload)
        STAGE((kt + 2) & 3, kt + 2);
        // wait only A(kt)'s gll: newest-10 = [gll(kt+2), B(kt)x8, gll(kt+1)]
        asm volatile("s_waitcnt vmcnt(10)" ::: "memory");
        __builtin_amdgcn_s_barrier();
        asm volatile("" ::: "memory");
        const char* base = ldsA[kt & 3];
        #pragma unroll
        for (int f = 0; f < 2; ++f)
            abf[f] = cvt8(*(const float4*)(base + ard[f][0]),
                          *(const float4*)(base + ard[f][1]));
        #pragma unroll
        for (int f = 0; f < 2; ++f)
            #pragma unroll
            for (int g = 0; g < 8; ++g)
                acc[f][g] = __builtin_amdgcn_mfma_f32_16x16x32_bf16(
                    abf[f], bfr[g], acc[f][g], 0, 0, 0);
    }
    #undef STAGE

    // ---- fused epilogue: pf store + u partials ----
    const int bidx = Mbase >> 12;
    const float* pqb = pq + (bidx << 9);
    float vv[8], pv[8];
    #pragma unroll
    for (int g = 0; g < 8; ++g) {
        const int c = w * 128 + g * 16 + fm;
        vv[g] = v[c];
        pv[g] = pqb[c];
    }
    #pragma unroll
    for (int f = 0; f < 2; ++f) {
        #pragma unroll
        for (int rr = 0; rr < 4; ++rr) {
            const int rloc = f * 16 + fkg * 4 + rr;
            float* prow = pf + (size_t)(Mbase + rloc) * HDIM + w * 128 + fm;
            float s = 0.0f;
            #pragma unroll
            for (int g = 0; g < 8; ++g) {
                const float val = acc[f][g][rr];
                __builtin_nontemporal_store(val, &prow[g * 16]);
                s += vv[g] * fast_tanh(val + pv[g]);
            }
            s += __shfl_xor(s, 1);
            s += __shfl_xor(s, 2);
            s += __shfl_xor(s, 4);
            s += __shfl_xor(s, 8);
            if (fm == 0) uls[rloc * 4 + w] = s;
        }
    }
    __syncthreads();
    if (t < 32) {
        const float4 p4 = *(const float4*)(uls + t * 4);
        const float u = p4.x + p4.y + p4.z + p4.w;
        logits[Mbase + t] = 10.0f * fast_tanh(u);
    }
}

extern "C" void kernel_launch(void* const* d_in, const int* in_sizes, int n_in,
                              void* d_out, int out_size, void* d_ws, size_t ws_size,
                              hipStream_t stream) {
    const float* features = (const float*)d_in[0];
    const float* query    = (const float*)d_in[1];
    const float* Wf       = (const float*)d_in[2];
    const float* Wq       = (const float*)d_in[3];
    const float* v        = (const float*)d_in[4];

    float* pf     = (float*)d_out;
    float* logits = (float*)d_out + 33554432;

    float* ws_pq  = (float*)d_ws;                    // 8192 f32  (32KB)
    short* ws_bsh = (short*)(ws_pq + 8192);          // 524288 bf16 (1MB)

    bshuf_kernel<<<256, 256, 0, stream>>>(Wf, ws_bsh);
    pq_kernel<<<16, 512, 0, stream>>>(query, Wq, ws_pq);
    gemm_kernel<<<2048, 256, 0, stream>>>(features, ws_bsh, ws_pq, v, pf, logits);
}